// Round 4
// baseline (312.524 us; speedup 1.0000x reference)
//
#include <hip/hip_runtime.h>

// Problem constants: B=64, T=512, D=1024, L=32
#define OUT_LOSS_IDX 1048576  // B*T*L

typedef __attribute__((ext_vector_type(4))) float f32x4;
typedef __attribute__((ext_vector_type(4))) int i32x4;
typedef __attribute__((ext_vector_type(8))) short bf16x8;

__device__ __forceinline__ unsigned short f32_to_bf16(float f) {
    unsigned u = __float_as_uint(f);
    unsigned r = (u + 0x7FFFu + ((u >> 16) & 1u)) >> 16;
    return (unsigned short)r;
}

// ---------------------------------------------------------------------------
// K0: W (1024x32 f32) -> Wt (32x1024 bf16) in workspace; zero the loss slot.
// ---------------------------------------------------------------------------
__global__ void k0_wt(const float* __restrict__ W, unsigned short* __restrict__ Wt,
                      float* __restrict__ loss) {
    int idx = blockIdx.x * 256 + threadIdx.x;   // 0..32767, coalesced read
    int k = idx >> 5, c = idx & 31;
    Wt[c * 1024 + k] = f32_to_bf16(W[idx]);
    if (idx == 0) loss[0] = 0.f;
}

// ---------------------------------------------------------------------------
// K1: logits = x*W + b (bf16 MFMA) + fused softmax. No LDS: A-frags straight
// from global, B-frags from global (64 KB -> L2-resident). 1 wave / 16 rows.
// ---------------------------------------------------------------------------
__global__ __launch_bounds__(64) void k1_gemm(
    const float* __restrict__ x, const unsigned short* __restrict__ Wt,
    const float* __restrict__ bias, float* __restrict__ logits,
    float* __restrict__ probs) {
    const int lane = threadIdx.x;
    const int m = lane & 15, quad = lane >> 4;
    const int r0 = blockIdx.x * 16;

    const float* xa = x + (size_t)(r0 + m) * 1024 + quad * 8;
    const unsigned short* wb0 = Wt + (size_t)m * 1024 + quad * 8;
    const unsigned short* wb1 = Wt + (size_t)(m + 16) * 1024 + quad * 8;

    f32x4 acc0 = {0.f, 0.f, 0.f, 0.f};
    f32x4 acc1 = {0.f, 0.f, 0.f, 0.f};

    #pragma unroll 4
    for (int ks = 0; ks < 32; ++ks) {
        f32x4 a0 = *(const f32x4*)(xa + ks * 32);
        f32x4 a1 = *(const f32x4*)(xa + ks * 32 + 4);
        bf16x8 b0 = *(const bf16x8*)(wb0 + ks * 32);
        bf16x8 b1 = *(const bf16x8*)(wb1 + ks * 32);
        bf16x8 af;
        af[0] = (short)f32_to_bf16(a0[0]); af[1] = (short)f32_to_bf16(a0[1]);
        af[2] = (short)f32_to_bf16(a0[2]); af[3] = (short)f32_to_bf16(a0[3]);
        af[4] = (short)f32_to_bf16(a1[0]); af[5] = (short)f32_to_bf16(a1[1]);
        af[6] = (short)f32_to_bf16(a1[2]); af[7] = (short)f32_to_bf16(a1[3]);
        acc0 = __builtin_amdgcn_mfma_f32_16x16x32_bf16(af, b0, acc0, 0, 0, 0);
        acc1 = __builtin_amdgcn_mfma_f32_16x16x32_bf16(af, b1, acc1, 0, 0, 0);
    }
    const float bc0 = bias[m], bc1 = bias[16 + m];
    #pragma unroll
    for (int r = 0; r < 4; ++r) {
        int row = r0 + quad * 4 + r;  // C/D: col=lane&15, row=quad*4+reg
        float l0 = acc0[r] + bc0;
        float l1 = acc1[r] + bc1;
        logits[row * 32 + m] = l0;
        logits[row * 32 + 16 + m] = l1;
        float mx = fmaxf(l0, l1);
        #pragma unroll
        for (int d = 1; d < 16; d <<= 1) mx = fmaxf(mx, __shfl_xor(mx, d, 64));
        float e0 = __expf(l0 - mx), e1 = __expf(l1 - mx);
        float s = e0 + e1;
        #pragma unroll
        for (int d = 1; d < 16; d <<= 1) s += __shfl_xor(s, d, 64);
        float inv = 1.0f / s;
        probs[row * 32 + m] = e0 * inv;
        probs[row * 32 + 16 + m] = e1 * inv;
    }
}

// ---------------------------------------------------------------------------
// K3: CRF forward (exp space) + fused gold score + atomic loss.
// Chain per step: ds_write p -> 8x broadcast ds_read_b128 -> 32-FMA tree
// -> *(elt*rcp(r0)) -> select. Rescale by r0 each step (r0 already in regs,
// zero-comm); logC accumulation off-chain. One wave per batch, 64 blocks.
// Lanes j and j+32 duplicate work (harmless, keeps wave64 issue simple).
// ---------------------------------------------------------------------------
__global__ __launch_bounds__(64, 1) void k3_crf(
    const float* __restrict__ logits, const int* __restrict__ mask,
    const int* __restrict__ labels, const float* __restrict__ trans,
    const float* __restrict__ start_t, const float* __restrict__ end_t,
    float* __restrict__ loss_out) {
    __shared__ float sElt[512 * 32];                     // exp(logits), 64 KB
    __shared__ __align__(16) float pbuf[2][32];          // double-buffered p
    __shared__ int smask[512];                           // 2 KB

    const int b = blockIdx.x, lane = threadIdx.x;
    const int j = lane & 31;
    const int base = b * 512;

    const float* gl = logits + (size_t)b * 16384;
    #pragma unroll 4
    for (int it = 0; it < 64; ++it) {
        int idx = it * 64 + lane;  // float4 index 0..4095
        f32x4 v = *(const f32x4*)&gl[idx * 4];
        f32x4 e = {__expf(v[0]), __expf(v[1]), __expf(v[2]), __expf(v[3])};
        *(f32x4*)&sElt[idx * 4] = e;
    }
    #pragma unroll
    for (int it = 0; it < 2; ++it) {
        int idx = it * 64 + lane;
        *(i32x4*)&smask[idx * 4] = *(const i32x4*)&mask[base + idx * 4];
    }
    __syncthreads();

    float tcE[32];  // exp(trans[i][j]) for all i — lane j's column
    #pragma unroll
    for (int i = 0; i < 32; ++i) tcE[i] = __expf(trans[i * 32 + j]);

    // t = 0
    float p = __expf(start_t[j]) * sElt[j];
    float logC = 0.f;
    pbuf[0][j] = p;
    __syncthreads();

    #pragma unroll 2
    for (int t = 1; t < 512; ++t) {
        const float* pb = pbuf[(t - 1) & 1];
        f32x4 r0 = *(const f32x4*)&pb[0];
        f32x4 r1 = *(const f32x4*)&pb[4];
        f32x4 r2 = *(const f32x4*)&pb[8];
        f32x4 r3 = *(const f32x4*)&pb[12];
        f32x4 r4 = *(const f32x4*)&pb[16];
        f32x4 r5 = *(const f32x4*)&pb[20];
        f32x4 r6 = *(const f32x4*)&pb[24];
        f32x4 r7 = *(const f32x4*)&pb[28];
        float elt = sElt[t * 32 + j];
        int mk = smask[t];
        float tmp = elt * __builtin_amdgcn_rcpf(r0[0]);  // off-chain vs FMA tree
        float s0 = 0.f, s1 = 0.f, s2 = 0.f, s3 = 0.f;
        s0 = fmaf(r0[0], tcE[0],  s0); s1 = fmaf(r0[1], tcE[1],  s1);
        s2 = fmaf(r0[2], tcE[2],  s2); s3 = fmaf(r0[3], tcE[3],  s3);
        s0 = fmaf(r1[0], tcE[4],  s0); s1 = fmaf(r1[1], tcE[5],  s1);
        s2 = fmaf(r1[2], tcE[6],  s2); s3 = fmaf(r1[3], tcE[7],  s3);
        s0 = fmaf(r2[0], tcE[8],  s0); s1 = fmaf(r2[1], tcE[9],  s1);
        s2 = fmaf(r2[2], tcE[10], s2); s3 = fmaf(r2[3], tcE[11], s3);
        s0 = fmaf(r3[0], tcE[12], s0); s1 = fmaf(r3[1], tcE[13], s1);
        s2 = fmaf(r3[2], tcE[14], s2); s3 = fmaf(r3[3], tcE[15], s3);
        s0 = fmaf(r4[0], tcE[16], s0); s1 = fmaf(r4[1], tcE[17], s1);
        s2 = fmaf(r4[2], tcE[18], s2); s3 = fmaf(r4[3], tcE[19], s3);
        s0 = fmaf(r5[0], tcE[20], s0); s1 = fmaf(r5[1], tcE[21], s1);
        s2 = fmaf(r5[2], tcE[22], s2); s3 = fmaf(r5[3], tcE[23], s3);
        s0 = fmaf(r6[0], tcE[24], s0); s1 = fmaf(r6[1], tcE[25], s1);
        s2 = fmaf(r6[2], tcE[26], s2); s3 = fmaf(r6[3], tcE[27], s3);
        s0 = fmaf(r7[0], tcE[28], s0); s1 = fmaf(r7[1], tcE[29], s1);
        s2 = fmaf(r7[2], tcE[30], s2); s3 = fmaf(r7[3], tcE[31], s3);
        float s = (s0 + s1) + (s2 + s3);
        float q = s * tmp;
        p = mk ? q : p;
        pbuf[t & 1][j] = p;
        logC += mk ? __logf(r0[0]) : 0.f;  // off-chain accumulator
    }

    // logZ_b = logC + logsumexp_j(log p_j + end_j)  (halves hold duplicates)
    float f = logC + __logf(p) + end_t[j];
    float mx = f;
    #pragma unroll
    for (int d = 1; d < 32; d <<= 1) mx = fmaxf(mx, __shfl_xor(mx, d, 64));
    float e = __expf(f - mx), se = e;
    #pragma unroll
    for (int d = 1; d < 32; d <<= 1) se += __shfl_xor(se, d, 64);
    float logZb = mx + __logf(se);  // every lane has it

    // ---- fused gold score: each lane handles 8 timesteps ----
    const int t0 = lane * 8;
    const int* lb = labels + base + t0;
    i32x4 la = *(const i32x4*)&lb[0];
    i32x4 lb2 = *(const i32x4*)&lb[4];
    int tg[8] = {la[0], la[1], la[2], la[3], lb2[0], lb2[1], lb2[2], lb2[3]};
    int prev = (lane == 0) ? 0 : labels[base + t0 - 1];
    float part = 0.f;
    int cnt = 0;
    #pragma unroll
    for (int r = 0; r < 8; ++r) {
        int t = t0 + r;
        int mk = smask[t];
        float mf = mk ? 1.f : 0.f;
        cnt += mk ? 1 : 0;
        int tag = tg[r];
        if (t > 0) part += trans[prev * 32 + tag] * mf;
        if (t < 511) part += __logf(sElt[t * 32 + tag]) * mf;
        prev = tag;
    }
    #pragma unroll
    for (int d = 1; d < 64; d <<= 1) {
        part += __shfl_xor(part, d, 64);
        cnt += __shfl_xor(cnt, d, 64);
    }
    if (lane == 0) {
        int len = cnt;
        int first = labels[base];
        int last = labels[base + len - 1];
        float g = part + start_t[first] + end_t[last];
        g += __logf(sElt[511 * 32 + last]) * (smask[511] ? 1.f : 0.f);
        atomicAdd(loss_out, logZb - g);
    }
}

extern "C" void kernel_launch(void* const* d_in, const int* in_sizes, int n_in,
                              void* d_out, int out_size, void* d_ws, size_t ws_size,
                              hipStream_t stream) {
    const float* x       = (const float*)d_in[0];
    const int* mk        = (const int*)d_in[1];   // bool mask promoted to int32
    const int* labels    = (const int*)d_in[2];
    const float* W       = (const float*)d_in[3];
    const float* bias    = (const float*)d_in[4];
    const float* trans   = (const float*)d_in[5];
    const float* start_t = (const float*)d_in[6];
    const float* end_t   = (const float*)d_in[7];

    float* probs = (float*)d_out;
    float* loss  = probs + OUT_LOSS_IDX;
    float* ws = (float*)d_ws;
    float* logits = ws;                                        // 1048576 f32 (4 MB)
    unsigned short* Wt = (unsigned short*)(ws + 1048576);      // 32768 bf16 (64 KB)

    k0_wt<<<128, 256, 0, stream>>>(W, Wt, loss);
    k1_gemm<<<2048, 64, 0, stream>>>(x, Wt, bias, logits, probs);
    k3_crf<<<64, 64, 0, stream>>>(logits, mk, labels, trans, start_t, end_t, loss);
}

// Round 5
// 239.371 us; speedup vs baseline: 1.3056x; 1.3056x over previous
//
#include <hip/hip_runtime.h>

// Problem constants: B=64, T=512, D=1024, L=32
#define OUT_LOSS_IDX 1048576  // B*T*L

typedef __attribute__((ext_vector_type(4)))  float f32x4;
typedef __attribute__((ext_vector_type(16))) float f32x16;
typedef __attribute__((ext_vector_type(4)))  int i32x4;
typedef __attribute__((ext_vector_type(4)))  unsigned u32x4;
typedef __attribute__((ext_vector_type(8)))  short bf16x8;

__device__ __forceinline__ unsigned short f32_to_bf16(float f) {
    unsigned u = __float_as_uint(f);
    unsigned r = (u + 0x7FFFu + ((u >> 16) & 1u)) >> 16;
    return (unsigned short)r;
}
// pack two f32 -> bf16 pair (round-half-up) in one dword: short0=lo, short1=hi
__device__ __forceinline__ unsigned packbf(float lo, float hi) {
    return __builtin_amdgcn_perm(__float_as_uint(hi) + 0x8000u,
                                 __float_as_uint(lo) + 0x8000u, 0x07060302u);
}

// ---------------------------------------------------------------------------
// K0: W (1024x32 f32) -> Wt (32x1024 bf16) in workspace; zero the loss slot.
// ---------------------------------------------------------------------------
__global__ void k0_wt(const float* __restrict__ W, unsigned short* __restrict__ Wt,
                      float* __restrict__ loss) {
    int idx = blockIdx.x * 256 + threadIdx.x;   // 0..32767, coalesced read
    int k = idx >> 5, c = idx & 31;
    Wt[c * 1024 + k] = f32_to_bf16(W[idx]);
    if (idx == 0) loss[0] = 0.f;
}

// ---------------------------------------------------------------------------
// K1: logits = x*W + b (bf16 MFMA) + fused softmax. A-frags straight from
// global, B-frags from global (64 KB -> L2-resident). 1 wave / 16 rows.
// (unchanged from r3 — evidence says total is insensitive to k1 structure)
// ---------------------------------------------------------------------------
__global__ __launch_bounds__(64) void k1_gemm(
    const float* __restrict__ x, const unsigned short* __restrict__ Wt,
    const float* __restrict__ bias, float* __restrict__ logits,
    float* __restrict__ probs) {
    const int lane = threadIdx.x;
    const int m = lane & 15, quad = lane >> 4;
    const int r0 = blockIdx.x * 16;

    const float* xa = x + (size_t)(r0 + m) * 1024 + quad * 8;
    const unsigned short* wb0 = Wt + (size_t)m * 1024 + quad * 8;
    const unsigned short* wb1 = Wt + (size_t)(m + 16) * 1024 + quad * 8;

    f32x4 acc0 = {0.f, 0.f, 0.f, 0.f};
    f32x4 acc1 = {0.f, 0.f, 0.f, 0.f};

    #pragma unroll 4
    for (int ks = 0; ks < 32; ++ks) {
        f32x4 a0 = *(const f32x4*)(xa + ks * 32);
        f32x4 a1 = *(const f32x4*)(xa + ks * 32 + 4);
        bf16x8 b0 = *(const bf16x8*)(wb0 + ks * 32);
        bf16x8 b1 = *(const bf16x8*)(wb1 + ks * 32);
        bf16x8 af;
        af[0] = (short)f32_to_bf16(a0[0]); af[1] = (short)f32_to_bf16(a0[1]);
        af[2] = (short)f32_to_bf16(a0[2]); af[3] = (short)f32_to_bf16(a0[3]);
        af[4] = (short)f32_to_bf16(a1[0]); af[5] = (short)f32_to_bf16(a1[1]);
        af[6] = (short)f32_to_bf16(a1[2]); af[7] = (short)f32_to_bf16(a1[3]);
        acc0 = __builtin_amdgcn_mfma_f32_16x16x32_bf16(af, b0, acc0, 0, 0, 0);
        acc1 = __builtin_amdgcn_mfma_f32_16x16x32_bf16(af, b1, acc1, 0, 0, 0);
    }
    const float bc0 = bias[m], bc1 = bias[16 + m];
    #pragma unroll
    for (int r = 0; r < 4; ++r) {
        int row = r0 + quad * 4 + r;  // C/D: col=lane&15, row=quad*4+reg
        float l0 = acc0[r] + bc0;
        float l1 = acc1[r] + bc1;
        logits[row * 32 + m] = l0;
        logits[row * 32 + 16 + m] = l1;
        float mx = fmaxf(l0, l1);
        #pragma unroll
        for (int d = 1; d < 16; d <<= 1) mx = fmaxf(mx, __shfl_xor(mx, d, 64));
        float e0 = __expf(l0 - mx), e1 = __expf(l1 - mx);
        float s = e0 + e1;
        #pragma unroll
        for (int d = 1; d < 16; d <<= 1) s += __shfl_xor(s, d, 64);
        float inv = 1.0f / s;
        probs[row * 32 + m] = e0 * inv;
        probs[row * 32 + 16 + m] = e1 * inv;
    }
}

// ---------------------------------------------------------------------------
// K3a: chunk transfer matrices. One wave per (batch, 32-step chunk):
// Q <- diag(elt_t) * (E^T * Q), Q0 = I. E^T is a constant MFMA A-operand.
// Block = 256 thr = 4 waves = 4 consecutive chunks of one batch.
// Output: Q (=G^T) f32 32x32 per chunk + log-scale, to workspace.
// ---------------------------------------------------------------------------
__global__ __launch_bounds__(256, 1) void k3a_chunks(
    const float* __restrict__ logits, const int* __restrict__ mask,
    const float* __restrict__ trans, float* __restrict__ Gws,
    float* __restrict__ chunkLog) {
    __shared__ float sElt[128 * 32];  // exp(logits) for this block's 128 steps (16 KB)
    __shared__ int smaskL[128];

    const int tid = threadIdx.x;
    const int b = blockIdx.x >> 2, a = blockIdx.x & 3;
    const int w = tid >> 6, lane = tid & 63;
    const int h = lane >> 5, col = lane & 31;

    // stage: steps t = 128a+1 .. 128a+128 (t=512 slot is junk, masked off)
    const float* src = logits + (size_t)b * 16384 + (128 * a + 1) * 32;
    #pragma unroll
    for (int q = 0; q < 4; ++q) {
        int slot = q * 256 + tid;  // f32x4 slots 0..1023
        f32x4 v = *(const f32x4*)&src[slot * 4];
        f32x4 e = {__expf(v[0]), __expf(v[1]), __expf(v[2]), __expf(v[3])};
        *(f32x4*)&sElt[slot * 4] = e;
    }
    if (tid < 128) {
        int t = 128 * a + 1 + tid;
        smaskL[tid] = (t < 512) ? mask[b * 512 + t] : 0;
    }
    __syncthreads();

    // constant A-operands: A1[m][k]=E[k][m] (k=8h+j), A2: k=16+8h+j
    bf16x8 a1, a2;
    #pragma unroll
    for (int j = 0; j < 8; ++j) {
        a1[j] = (short)f32_to_bf16(__expf(trans[(8 * h + j) * 32 + col]));
        a2[j] = (short)f32_to_bf16(__expf(trans[(16 + 8 * h + j) * 32 + col]));
    }

    // Q = I in C/D layout: row=(r&3)+8*(r>>2)+4h, col=lane&31
    float c[16];
    #pragma unroll
    for (int r = 0; r < 16; ++r)
        c[r] = (((r & 3) + 8 * (r >> 2) + 4 * h) == col) ? 1.f : 0.f;
    int esum = 0;

    for (int tl = 0; tl < 32; ++tl) {
        const int tt = 32 * w + tl;
        // C/D -> B-frag: pack pairs to bf16, swap halves (col stays in lane)
        unsigned d0 = packbf(c[0],  c[1]),  d1 = packbf(c[2],  c[3]);
        unsigned d2 = packbf(c[4],  c[5]),  d3 = packbf(c[6],  c[7]);
        unsigned d4 = packbf(c[8],  c[9]),  d5 = packbf(c[10], c[11]);
        unsigned d6 = packbf(c[12], c[13]), d7 = packbf(c[14], c[15]);
        unsigned x0 = (unsigned)__shfl_xor((int)d0, 32, 64);
        unsigned x1 = (unsigned)__shfl_xor((int)d1, 32, 64);
        unsigned x2 = (unsigned)__shfl_xor((int)d2, 32, 64);
        unsigned x3 = (unsigned)__shfl_xor((int)d3, 32, 64);
        unsigned x4 = (unsigned)__shfl_xor((int)d4, 32, 64);
        unsigned x5 = (unsigned)__shfl_xor((int)d5, 32, 64);
        unsigned x6 = (unsigned)__shfl_xor((int)d6, 32, 64);
        unsigned x7 = (unsigned)__shfl_xor((int)d7, 32, 64);
        u32x4 b0w = {h ? x2 : d0, h ? x3 : d1, h ? d2 : x0, h ? d3 : x1};
        u32x4 b1w = {h ? x6 : d4, h ? x7 : d5, h ? d6 : x4, h ? d7 : x5};
        bf16x8 b0 = __builtin_bit_cast(bf16x8, b0w);
        bf16x8 b1 = __builtin_bit_cast(bf16x8, b1w);

        f32x16 zz = {};
        f32x16 acc = __builtin_amdgcn_mfma_f32_32x32x16_bf16(a1, b0, zz, 0, 0, 0);
        acc = __builtin_amdgcn_mfma_f32_32x32x16_bf16(a2, b1, acc, 0, 0, 0);

        const f32x4* ep = (const f32x4*)&sElt[tt * 32];
        f32x4 e0 = ep[h], e1 = ep[2 + h], e2 = ep[4 + h], e3 = ep[6 + h];
        const int mk = smaskL[tt];

        // dynamic rescale from Q[0][0] (uniform scalar)
        int sb = __builtin_amdgcn_readfirstlane(__float_as_int(c[0]));
        int ee = ((sb >> 23) & 0xff) - 127;
        ee = ee < -60 ? -60 : (ee > 60 ? 60 : ee);
        float sc = __int_as_float((127 - ee) << 23);
        esum += ee;

        #pragma unroll
        for (int r = 0; r < 16; ++r) {
            float ev = (r < 4 ? e0[r & 3] : r < 8 ? e1[r & 3] : r < 12 ? e2[r & 3] : e3[r & 3]);
            float qn = acc[r] * (ev * sc);
            float qa = c[r] * sc;
            c[r] = mk ? qn : qa;
        }
    }

    const int cc = 4 * a + w;
    float* gw = Gws + (((size_t)(b * 16 + cc)) << 10);
    #pragma unroll
    for (int r = 0; r < 16; ++r)
        gw[((r & 3) + 8 * (r >> 2) + 4 * h) * 32 + col] = c[r];
    if (lane == 0)
        chunkLog[b * 16 + cc] = (float)esum * 0.6931471805599453f;
}

// ---------------------------------------------------------------------------
// K3b: apply 16 chunk matrices sequentially per batch (one wave per batch),
// then logZ + fused gold score + atomic loss. alpha'_j = sum_i alpha_i*G[i][j]
// = sum_i alpha_i * Q[j][i]  ->  lane j reads Q row j (contiguous 128 B).
// ---------------------------------------------------------------------------
__global__ __launch_bounds__(64, 1) void k3b_combine(
    const float* __restrict__ logits, const int* __restrict__ mask,
    const int* __restrict__ labels, const float* __restrict__ trans,
    const float* __restrict__ start_t, const float* __restrict__ end_t,
    const float* __restrict__ Gws, const float* __restrict__ chunkLog,
    float* __restrict__ loss_out) {
    __shared__ __align__(16) float pbuf[2][32];
    __shared__ int smaskL[512];

    const int b = blockIdx.x, lane = threadIdx.x;
    const int j = lane & 31;
    const int base = b * 512;

    #pragma unroll
    for (int it = 0; it < 2; ++it) {
        int idx = it * 64 + lane;
        *(i32x4*)&smaskL[idx * 4] = *(const i32x4*)&mask[base + idx * 4];
    }
    float p = __expf(start_t[j] + logits[(size_t)b * 16384 + j]);  // alpha0
    float logC = 0.f;
    pbuf[0][j] = p;
    __syncthreads();

    for (int cc = 0; cc < 16; ++cc) {
        const float* g = Gws + ((((size_t)(b * 16 + cc)) << 10) + j * 32);
        f32x4 g0 = *(const f32x4*)&g[0],  g1 = *(const f32x4*)&g[4];
        f32x4 g2 = *(const f32x4*)&g[8],  g3 = *(const f32x4*)&g[12];
        f32x4 g4 = *(const f32x4*)&g[16], g5 = *(const f32x4*)&g[20];
        f32x4 g6 = *(const f32x4*)&g[24], g7 = *(const f32x4*)&g[28];
        const float* pb = pbuf[cc & 1];
        f32x4 p0 = *(const f32x4*)&pb[0],  p1 = *(const f32x4*)&pb[4];
        f32x4 p2 = *(const f32x4*)&pb[8],  p3 = *(const f32x4*)&pb[12];
        f32x4 p4 = *(const f32x4*)&pb[16], p5 = *(const f32x4*)&pb[20];
        f32x4 p6 = *(const f32x4*)&pb[24], p7 = *(const f32x4*)&pb[28];
        float r0 = p0[0];
        float s0 = 0.f, s1 = 0.f, s2 = 0.f, s3 = 0.f;
        s0 = fmaf(p0[0], g0[0], s0); s1 = fmaf(p0[1], g0[1], s1);
        s2 = fmaf(p0[2], g0[2], s2); s3 = fmaf(p0[3], g0[3], s3);
        s0 = fmaf(p1[0], g1[0], s0); s1 = fmaf(p1[1], g1[1], s1);
        s2 = fmaf(p1[2], g1[2], s2); s3 = fmaf(p1[3], g1[3], s3);
        s0 = fmaf(p2[0], g2[0], s0); s1 = fmaf(p2[1], g2[1], s1);
        s2 = fmaf(p2[2], g2[2], s2); s3 = fmaf(p2[3], g2[3], s3);
        s0 = fmaf(p3[0], g3[0], s0); s1 = fmaf(p3[1], g3[1], s1);
        s2 = fmaf(p3[2], g3[2], s2); s3 = fmaf(p3[3], g3[3], s3);
        s0 = fmaf(p4[0], g4[0], s0); s1 = fmaf(p4[1], g4[1], s1);
        s2 = fmaf(p4[2], g4[2], s2); s3 = fmaf(p4[3], g4[3], s3);
        s0 = fmaf(p5[0], g5[0], s0); s1 = fmaf(p5[1], g5[1], s1);
        s2 = fmaf(p5[2], g5[2], s2); s3 = fmaf(p5[3], g5[3], s3);
        s0 = fmaf(p6[0], g6[0], s0); s1 = fmaf(p6[1], g6[1], s1);
        s2 = fmaf(p6[2], g6[2], s2); s3 = fmaf(p6[3], g6[3], s3);
        s0 = fmaf(p7[0], g7[0], s0); s1 = fmaf(p7[1], g7[1], s1);
        s2 = fmaf(p7[2], g7[2], s2); s3 = fmaf(p7[3], g7[3], s3);
        float s = (s0 + s1) + (s2 + s3);
        p = s * __builtin_amdgcn_rcpf(r0);
        pbuf[(cc + 1) & 1][j] = p;
        logC += __logf(r0);
    }
    float clsum = 0.f;
    #pragma unroll
    for (int cc = 0; cc < 16; ++cc) clsum += chunkLog[b * 16 + cc];

    float f = logC + clsum + __logf(p) + end_t[j];
    float mx = f;
    #pragma unroll
    for (int d = 1; d < 32; d <<= 1) mx = fmaxf(mx, __shfl_xor(mx, d, 64));
    float e = __expf(f - mx), se = e;
    #pragma unroll
    for (int d = 1; d < 32; d <<= 1) se += __shfl_xor(se, d, 64);
    float logZb = mx + __logf(se);

    // ---- fused gold score: each lane handles 8 timesteps ----
    const int t0 = lane * 8;
    const int* lb = labels + base + t0;
    i32x4 la = *(const i32x4*)&lb[0];
    i32x4 lc = *(const i32x4*)&lb[4];
    int tg[8] = {la[0], la[1], la[2], la[3], lc[0], lc[1], lc[2], lc[3]};
    int prev = (lane == 0) ? 0 : labels[base + t0 - 1];
    float part = 0.f;
    int cnt = 0;
    #pragma unroll
    for (int r = 0; r < 8; ++r) {
        int t = t0 + r;
        int mk = smaskL[t];
        float mf = mk ? 1.f : 0.f;
        cnt += mk ? 1 : 0;
        int tag = tg[r];
        if (t > 0) part += trans[prev * 32 + tag] * mf;
        if (t < 511) part += logits[(size_t)b * 16384 + t * 32 + tag] * mf;
        prev = tag;
    }
    #pragma unroll
    for (int d = 1; d < 64; d <<= 1) {
        part += __shfl_xor(part, d, 64);
        cnt += __shfl_xor(cnt, d, 64);
    }
    if (lane == 0) {
        int len = cnt;
        int first = labels[base];
        int last = labels[base + len - 1];
        float g = part + start_t[first] + end_t[last];
        g += logits[(size_t)b * 16384 + 511 * 32 + last] * (smaskL[511] ? 1.f : 0.f);
        atomicAdd(loss_out, logZb - g);
    }
}

extern "C" void kernel_launch(void* const* d_in, const int* in_sizes, int n_in,
                              void* d_out, int out_size, void* d_ws, size_t ws_size,
                              hipStream_t stream) {
    const float* x       = (const float*)d_in[0];
    const int* mk        = (const int*)d_in[1];   // bool mask promoted to int32
    const int* labels    = (const int*)d_in[2];
    const float* W       = (const float*)d_in[3];
    const float* bias    = (const float*)d_in[4];
    const float* trans   = (const float*)d_in[5];
    const float* start_t = (const float*)d_in[6];
    const float* end_t   = (const float*)d_in[7];

    float* probs = (float*)d_out;
    float* loss  = probs + OUT_LOSS_IDX;
    float* ws = (float*)d_ws;
    float* logits = ws;                                   // 1048576 f32 (4 MB)
    unsigned short* Wt = (unsigned short*)(ws + 1048576); // 32768 bf16 (64 KB); dead after k1
    float* Gws = ws + 1048576 + 16384;                    // 1048576 f32 (4 MB)
    float* chunkLog = Gws + 1048576;                      // 1024 f32

    k0_wt<<<128, 256, 0, stream>>>(W, Wt, loss);
    k1_gemm<<<2048, 64, 0, stream>>>(x, Wt, bias, logits, probs);
    k3a_chunks<<<256, 256, 0, stream>>>(logits, mk, trans, Gws, chunkLog);
    k3b_combine<<<64, 64, 0, stream>>>(logits, mk, labels, trans, start_t, end_t,
                                       Gws, chunkLog, loss);
}